// Round 4
// baseline (4049.417 us; speedup 1.0000x reference)
//
#include <hip/hip_runtime.h>
#include <math.h>

#define NTHR 1024

constexpr int EG_STRIDE = 16384;   // floats per batch: e1 only (128 rows x 128)

__device__ __forceinline__ int xoff(int l) { return 512 - (512 >> l); }   // l in 0..7

// ---- one MLP chunk: eout[r] = relu(z[r] @ W1 + b1 [+ lab]) @ W2 + b2, r < C
// layer1: 16 waves = 8 k-groups (32 k) x 2 col-halves, 2 cols/lane, acc in regs.
// layer2: 16 waves = 16 k-groups (16 k), 2 cols/lane, acc in regs.
// R4 latency schedule: R3 measured ~3.5 us per ROW of chunk cost -> per-row
// serialized ds_read->waitcnt->FMA chains. Fix: (a) batch all C z-reads of an
// iteration into z[C] regs (one LDS wait/iter, not C), (b) prefetch next
// iteration's 4 weight float2s before consuming current (FMAs wait at
// vmcnt(4): current weights resident, next in flight -> L2 latency hidden
// under the iteration body). `#pragma unroll 1` keeps the scheduler from
// re-flattening (R1/R2's 21 GB spill lesson). Live ~80 VGPR, cap 128 via
// waves_per_eu(4,4); row loops fully unrolled -> static indexing, no scratch.
template <int C>
__device__ __forceinline__ void mlp_chunk(
    const float* zl, int zstr,
    const float* __restrict__ W1, const float* __restrict__ B1,
    const float* __restrict__ W2, const float* __restrict__ B2,
    const float* lab, bool uselab, const int* u1h, int done,
    float* red, float* h, float* eout)
{
  const int t  = threadIdx.x;
  const int wv = t >> 6;
  const int ln = t & 63;
  // ---------- layer 1 ----------
  {
    const int kg = wv >> 1;                       // k-group: 32 k
    const int c1 = (wv & 1) * 128 + 2 * ln;       // col pair within 256
    const float* wb = W1 + 32 * kg * 256 + c1;
    const float* zb = zl + 32 * kg;
    float2 acc[C];
#pragma unroll
    for (int r = 0; r < C; ++r) acc[r] = make_float2(0.f, 0.f);
    float2 w0 = *reinterpret_cast<const float2*>(wb);
    float2 w1 = *reinterpret_cast<const float2*>(wb + 256);
    float2 w2 = *reinterpret_cast<const float2*>(wb + 512);
    float2 w3 = *reinterpret_cast<const float2*>(wb + 768);
#pragma unroll 1
    for (int blk = 0; blk < 8; ++blk) {           // 8 serial blocks of 4 k
      const float* wn = wb + 4 * ((blk < 7) ? blk + 1 : 7) * 256;
      const float2 n0 = *reinterpret_cast<const float2*>(wn);
      const float2 n1 = *reinterpret_cast<const float2*>(wn + 256);
      const float2 n2 = *reinterpret_cast<const float2*>(wn + 512);
      const float2 n3 = *reinterpret_cast<const float2*>(wn + 768);
      float4 z[C];
#pragma unroll
      for (int r = 0; r < C; ++r)
        z[r] = *reinterpret_cast<const float4*>(zb + r * zstr + 4 * blk);
#pragma unroll
      for (int r = 0; r < C; ++r) {
        acc[r].x = fmaf(z[r].x,w0.x, fmaf(z[r].y,w1.x, fmaf(z[r].z,w2.x, fmaf(z[r].w,w3.x, acc[r].x))));
        acc[r].y = fmaf(z[r].x,w0.y, fmaf(z[r].y,w1.y, fmaf(z[r].z,w2.y, fmaf(z[r].w,w3.y, acc[r].y))));
      }
      w0 = n0; w1 = n1; w2 = n2; w3 = n3;
    }
#pragma unroll
    for (int r = 0; r < C; ++r)
      *reinterpret_cast<float2*>(red + (kg * C + r) * 256 + c1) = acc[r];
  }
  __syncthreads();
  // ---------- reduce1 + bias (+lab) + relu -> h ----------
  if (t < 128 * C) {
    const int r  = t >> 7;
    const int c0 = 2 * (t & 127);
    float2 s = *reinterpret_cast<const float2*>(B1 + c0);
    if (uselab) {
      const int j = u1h[done + r] & 1;
      const float2 lv = *reinterpret_cast<const float2*>(lab + j * 256 + c0);
      s.x += lv.x; s.y += lv.y;
    }
#pragma unroll
    for (int q = 0; q < 8; ++q) {
      const float2 p = *reinterpret_cast<const float2*>(red + (q * C + r) * 256 + c0);
      s.x += p.x; s.y += p.y;
    }
    s.x = fmaxf(s.x, 0.f); s.y = fmaxf(s.y, 0.f);
    *reinterpret_cast<float2*>(h + r * 256 + c0) = s;
  }
  __syncthreads();
  // ---------- layer 2 ----------
  {
    const int c2 = 2 * ln;
    const float* wb2 = W2 + 16 * wv * 128 + c2;
    const float* hb = h + 16 * wv;
    float2 acc[C];
#pragma unroll
    for (int r = 0; r < C; ++r) acc[r] = make_float2(0.f, 0.f);
    float2 w0 = *reinterpret_cast<const float2*>(wb2);
    float2 w1 = *reinterpret_cast<const float2*>(wb2 + 128);
    float2 w2 = *reinterpret_cast<const float2*>(wb2 + 256);
    float2 w3 = *reinterpret_cast<const float2*>(wb2 + 384);
#pragma unroll 1
    for (int blk = 0; blk < 4; ++blk) {           // 4 serial blocks of 4 k
      const float* wn = wb2 + 4 * ((blk < 3) ? blk + 1 : 3) * 128;
      const float2 n0 = *reinterpret_cast<const float2*>(wn);
      const float2 n1 = *reinterpret_cast<const float2*>(wn + 128);
      const float2 n2 = *reinterpret_cast<const float2*>(wn + 256);
      const float2 n3 = *reinterpret_cast<const float2*>(wn + 384);
      float4 hv[C];
#pragma unroll
      for (int r = 0; r < C; ++r)
        hv[r] = *reinterpret_cast<const float4*>(hb + r * 256 + 4 * blk);
#pragma unroll
      for (int r = 0; r < C; ++r) {
        acc[r].x = fmaf(hv[r].x,w0.x, fmaf(hv[r].y,w1.x, fmaf(hv[r].z,w2.x, fmaf(hv[r].w,w3.x, acc[r].x))));
        acc[r].y = fmaf(hv[r].x,w0.y, fmaf(hv[r].y,w1.y, fmaf(hv[r].z,w2.y, fmaf(hv[r].w,w3.y, acc[r].y))));
      }
      w0 = n0; w1 = n1; w2 = n2; w3 = n3;
    }
#pragma unroll
    for (int r = 0; r < C; ++r)
      *reinterpret_cast<float2*>(red + (wv * C + r) * 128 + c2) = acc[r];
  }
  __syncthreads();
  // ---------- reduce2 + bias -> eout ----------
  if (t < 64 * C) {
    const int r  = t >> 6;
    const int c0 = 2 * (t & 63);
    float2 s = *reinterpret_cast<const float2*>(B2 + c0);
#pragma unroll
    for (int q = 0; q < 16; ++q) {
      const float2 p = *reinterpret_cast<const float2*>(red + (q * C + r) * 128 + c0);
      s.x += p.x; s.y += p.y;
    }
    *reinterpret_cast<float2*>(eout + r * 128 + c0) = s;
  }
  __syncthreads();
}

__global__ void sc_setup(const int* __restrict__ info_set,
                         const float* __restrict__ E_obs,
                         const float* __restrict__ E_lab,
                         const float* __restrict__ Wb1,
                         int* __restrict__ pos2k, float* __restrict__ lab1,
                         float* __restrict__ eroot)
{
  const int t = threadIdx.x;   // 256 threads
  pos2k[t] = -1;
  __syncthreads();
  if (t < 128) pos2k[info_set[t]] = t;
  eroot[t] = E_obs[2 * 128 + (t & 127)];
  for (int j = 0; j < 2; ++j) {
    float s = 0.0f;
    for (int k = 0; k < 128; ++k)
      s = fmaf(E_lab[j * 128 + k], Wb1[(256 + k) * 256 + t], s);
    lab1[j * 256 + t] = s;
  }
}

__global__ __launch_bounds__(NTHR)
__attribute__((amdgpu_waves_per_eu(4, 4)))   // 16 waves, 1 block/CU -> cap 128 VGPR
void sc_main(const int* __restrict__ info_bits, const float* __restrict__ rin,
             const float* __restrict__ Wc1, const float* __restrict__ bc1,
             const float* __restrict__ Wc2, const float* __restrict__ bc2,
             const float* __restrict__ Wb1, const float* __restrict__ bb1,
             const float* __restrict__ Wb2, const float* __restrict__ bb2,
             const float* __restrict__ Wl, const float* __restrict__ bl,
             const int* __restrict__ pos2k, const float* __restrict__ lab1_g,
             const float* __restrict__ eroot_g,
             float* __restrict__ wsall, float* __restrict__ out)
{
  const int b = blockIdx.x;
  const int t = threadIdx.x;
  float* e1g = wsall + (size_t)b * EG_STRIDE;      // level-1 e (global)

  __shared__ __align__(16) float red[16384];       // 64 KB split-K partials
  __shared__ __align__(16) float h_lds[2048];      //  8 KB hidden
  __shared__ __align__(16) float zstage[2048];     //  8 KB staged z / lvl-0 variants
  __shared__ __align__(16) float e2[8192];         // 32 KB level-2 e
  __shared__ __align__(16) float e3[4096];         // 16 KB level-3 e
  __shared__ __align__(16) float e4[2048];         //  8 KB level-4 e
  __shared__ __align__(16) float e5678[1920];      // levels 5..8: 8,4,2,1 rows
  __shared__ __align__(16) float lab_lds[512];
  __shared__ __align__(16) float eroot[256];
  __shared__ float rrow[256];
  __shared__ float wl_lds[132];                    // Wl[128] + bl at [128]
  __shared__ int   xh[520];
  __shared__ int   ibits[128];
  __shared__ int   p2k_l[256];

  float* xO = out;
  float* fO = out + 32768;
  float* uO = out + 65536;
  float* pO = out + 98304;
  float* rO = out + 131072;

  // ---- prologue: preload constants, hoist input-independent outputs ----
  if (t < 512) lab_lds[t] = lab1_g[t];
  if (t < 256) {
    eroot[t]  = eroot_g[t];
    const int k = pos2k[t];
    p2k_l[t]  = k;
    const float rv = rin[b * 256 + t];
    rrow[t]   = rv;
    rO[b * 256 + t] = rv;
    fO[b * 256 + t] = (k >= 0) ? 2.0f : 1.0f;
  }
  if (t < 128) { ibits[t] = info_bits[b * 128 + t]; wl_lds[t] = Wl[t]; }
  if (t == 128) wl_lds[128] = bl[0];
  if (t == 0) { xh[512] = 0; xh[513] = 1; }        // constant u1h for lvl-0 bit
  __syncthreads();

  // ---- generic level runner (levels 1..7, all-LDS z) ----
  auto run_level = [&](int l, bool isbit) {
    const int rows = 128 >> l;
    const float* W1 = isbit ? Wb1 : Wc1;
    const float* B1 = isbit ? bb1 : bc1;
    const float* W2 = isbit ? Wb2 : Wc2;
    const float* B2 = isbit ? bb2 : bc2;
    const int* u1h = xh + xoff(l);
    float* ein; float* eo;
    switch (l) {
      case 1:  ein = nullptr;        eo = e2;            break;
      case 2:  ein = e2;             eo = e3;            break;
      case 3:  ein = e3;             eo = e4;            break;
      case 4:  ein = e4;             eo = e5678;         break;
      case 5:  ein = e5678;          eo = e5678 + 1024;  break;
      case 6:  ein = e5678 + 1024;   eo = e5678 + 1536;  break;
      default: ein = e5678 + 1536;   eo = e5678 + 1792;  break;
    }
    int done = 0;
    while (done < rows) {
      int c = rows - done; if (c > 8) c = 8;
      const float* zl;
      if (l == 1) {   // stage global e1 chunk -> LDS (coalesced, one barrier)
        const float2* src = reinterpret_cast<const float2*>(e1g + done * 256);
        const int n2 = c * 128;
        for (int i2 = t; i2 < n2; i2 += NTHR)
          reinterpret_cast<float2*>(zstage)[i2] = src[i2];
        __syncthreads();
        zl = zstage;
      } else {
        zl = ein + done * 256;
      }
      float* eoc = eo + done * 128;
      if      (c == 8) mlp_chunk<8>(zl, 256, W1, B1, W2, B2, lab_lds, isbit, u1h, done, red, h_lds, eoc);
      else if (c == 4) mlp_chunk<4>(zl, 256, W1, B1, W2, B2, lab_lds, isbit, u1h, done, red, h_lds, eoc);
      else if (c == 2) mlp_chunk<2>(zl, 256, W1, B1, W2, B2, lab_lds, isbit, u1h, done, red, h_lds, eoc);
      else             mlp_chunk<1>(zl, 256, W1, B1, W2, B2, lab_lds, isbit, u1h, done, red, h_lds, eoc);
      done += c;
    }
  };

  // ---- level 0 special: check rows all identical (z = eroot); bit rows take
  // only 2 values (label j in {0,1}). Compute 1 (check) or 2 (bit) rows, then
  // broadcast/scatter into e1. ----
  auto run_level0 = [&](bool isbit) {
    if (!isbit) {
      mlp_chunk<1>(eroot, 0, Wc1, bc1, Wc2, bc2, lab_lds, false, xh, 0, red, h_lds, zstage);
      for (int i4 = t; i4 < 4096; i4 += NTHR)
        reinterpret_cast<float4*>(e1g)[i4] =
            reinterpret_cast<const float4*>(zstage)[i4 & 31];
    } else {
      mlp_chunk<2>(eroot, 0, Wb1, bb1, Wb2, bb2, lab_lds, true, xh + 512, 0, red, h_lds, zstage);
      for (int i4 = t; i4 < 4096; i4 += NTHR)
        reinterpret_cast<float4*>(e1g)[i4] =
            reinterpret_cast<const float4*>(zstage)[(xh[i4 >> 5] & 1) * 32 + (i4 & 31)];
    }
    __syncthreads();
  };

  auto do_leaf = [&](int i) {
    if (t < 64) {
      const float* e = e5678 + 1792;
      float partial = e[t] * wl_lds[t] + e[t + 64] * wl_lds[t + 64];
#pragma unroll
      for (int m = 32; m >= 1; m >>= 1) partial += __shfl_xor(partial, m);
      if (t == 0) {
        const float tv = partial + wl_lds[128];
        const float p  = 1.0f / (1.0f + expf(-tv));
        const float rv = rrow[i];
        const int  hd     = (rv > p) ? 1 : 0;
        const bool frozen = fabsf(p - 0.5f) > 0.25f;
        const int  k  = p2k_l[i];
        const int  fc = (k >= 0) ? ibits[k] : 2;
        const int  x  = (fc == 2 || frozen) ? hd : fc;
        xh[xoff(7) + (i & 1)] = x;
        pO[b * 256 + i] = p;
        uO[b * 256 + i] = (float)x;
      }
    }
    __syncthreads();
  };

  auto do_combine = [&](int l, int side) {
    const int n = 256 >> l, half = n >> 1;
    if (t < half) {
      const int u1 = xh[xoff(l) + t];
      const int u2 = xh[xoff(l) + half + t];
      if (l > 0) {
        const int base = xoff(l - 1) + side * n;
        xh[base + 2 * t]     = u1 ^ u2;
        xh[base + 2 * t + 1] = u2;
      } else {
        xO[b * 256 + 2 * t]     = (float)(u1 ^ u2);
        xO[b * 256 + 2 * t + 1] = (float)u2;
      }
    }
    __syncthreads();
  };

  // ---- SC traversal ----
  int i = 0, l = 0;
  bool isbit = false;
  while (true) {
    if (l == 0) run_level0(isbit);
    else        run_level(l, isbit);
    if (l < 7) { ++l; isbit = false; continue; }
    do_leaf(i);
    if (i == 255) break;
    ++i;
    const int s = __builtin_ctz(i);
    for (int j = 1; j <= s; ++j) do_combine(8 - j, (j < s) ? 1 : 0);
    l = 7 - s;
    isbit = true;
  }
  for (int j = 1; j <= 8; ++j) do_combine(8 - j, 1);
}

extern "C" void kernel_launch(void* const* d_in, const int* in_sizes, int n_in,
                              void* d_out, int out_size, void* d_ws, size_t ws_size,
                              hipStream_t stream)
{
  const int*   info_bits = (const int*)  d_in[0];
  const float* rin       = (const float*)d_in[1];
  const int*   info_set  = (const int*)  d_in[2];
  const float* E_obs     = (const float*)d_in[3];
  const float* E_lab     = (const float*)d_in[4];
  const float* Wc1 = (const float*)d_in[5];
  const float* bc1 = (const float*)d_in[6];
  const float* Wc2 = (const float*)d_in[7];
  const float* bc2 = (const float*)d_in[8];
  const float* Wb1 = (const float*)d_in[9];
  const float* bb1 = (const float*)d_in[10];
  const float* Wb2 = (const float*)d_in[11];
  const float* bb2 = (const float*)d_in[12];
  const float* Wl  = (const float*)d_in[13];
  const float* bl  = (const float*)d_in[14];

  int*   pos2k = (int*)d_ws;                 // 256 ints
  float* lab1  = (float*)d_ws + 256;         // 512 floats
  float* eroot = (float*)d_ws + 768;         // 256 floats
  float* wsall = (float*)d_ws + 1024;        // 128 x EG_STRIDE floats

  hipLaunchKernelGGL(sc_setup, dim3(1), dim3(256), 0, stream,
                     info_set, E_obs, E_lab, Wb1, pos2k, lab1, eroot);
  hipLaunchKernelGGL(sc_main, dim3(128), dim3(NTHR), 0, stream,
                     info_bits, rin,
                     Wc1, bc1, Wc2, bc2, Wb1, bb1, Wb2, bb2, Wl, bl,
                     pos2k, lab1, eroot, wsall, (float*)d_out);
}

// Round 5
// 3874.284 us; speedup vs baseline: 1.0452x; 1.0452x over previous
//
#include <hip/hip_runtime.h>
#include <math.h>

#define NTHR 1024

constexpr int EG_STRIDE = 16384;   // floats per batch: e1 only (128 rows x 128)

__device__ __forceinline__ int xoff(int l) { return 512 - (512 >> l); }   // l in 0..7

// ---- one MLP chunk: eout[r] = relu(z[r] @ W1 + b1 [+ lab]) @ W2 + b2, r < C
// (levels 0..4) layer1: 16 waves = 8 kg (32k) x 2 col-halves, 2 cols/lane.
// layer2: 16 waves = 16 kg (16k), 2 cols/lane. `#pragma unroll 1` on k-block
// loops is load-bearing: R1/R2 fully unrolled them, the list scheduler hoisted
// ~32 global loads past the 64-VGPR cap and spilled 21 GB (measured).
template <int C>
__device__ __forceinline__ void mlp_chunk(
    const float* zl, int zstr,
    const float* __restrict__ W1, const float* __restrict__ B1,
    const float* __restrict__ W2, const float* __restrict__ B2,
    const float* lab, bool uselab, const int* u1h, int done,
    float* red, float* h, float* eout)
{
  const int t  = threadIdx.x;
  const int wv = t >> 6;
  const int ln = t & 63;
  // ---------- layer 1 ----------
  {
    const int kg = wv >> 1;
    const int c1 = (wv & 1) * 128 + 2 * ln;
    const float* wb = W1 + 32 * kg * 256 + c1;
    const float* zb = zl + 32 * kg;
    float2 acc[C];
#pragma unroll
    for (int r = 0; r < C; ++r) acc[r] = make_float2(0.f, 0.f);
#pragma unroll 1
    for (int blk = 0; blk < 8; ++blk) {
      const float* wp = wb + 4 * blk * 256;
      const float2 w0 = *reinterpret_cast<const float2*>(wp);
      const float2 w1 = *reinterpret_cast<const float2*>(wp + 256);
      const float2 w2 = *reinterpret_cast<const float2*>(wp + 512);
      const float2 w3 = *reinterpret_cast<const float2*>(wp + 768);
#pragma unroll
      for (int r = 0; r < C; ++r) {
        const float4 z = *reinterpret_cast<const float4*>(zb + r * zstr + 4 * blk);
        acc[r].x = fmaf(z.x,w0.x, fmaf(z.y,w1.x, fmaf(z.z,w2.x, fmaf(z.w,w3.x, acc[r].x))));
        acc[r].y = fmaf(z.x,w0.y, fmaf(z.y,w1.y, fmaf(z.z,w2.y, fmaf(z.w,w3.y, acc[r].y))));
      }
    }
#pragma unroll
    for (int r = 0; r < C; ++r)
      *reinterpret_cast<float2*>(red + (kg * C + r) * 256 + c1) = acc[r];
  }
  __syncthreads();
  // ---------- reduce1 + bias (+lab) + relu -> h ----------
  if (t < 128 * C) {
    const int r  = t >> 7;
    const int c0 = 2 * (t & 127);
    float2 s = *reinterpret_cast<const float2*>(B1 + c0);
    if (uselab) {
      const int j = u1h[done + r] & 1;
      const float2 lv = *reinterpret_cast<const float2*>(lab + j * 256 + c0);
      s.x += lv.x; s.y += lv.y;
    }
#pragma unroll
    for (int q = 0; q < 8; ++q) {
      const float2 p = *reinterpret_cast<const float2*>(red + (q * C + r) * 256 + c0);
      s.x += p.x; s.y += p.y;
    }
    s.x = fmaxf(s.x, 0.f); s.y = fmaxf(s.y, 0.f);
    *reinterpret_cast<float2*>(h + r * 256 + c0) = s;
  }
  __syncthreads();
  // ---------- layer 2 ----------
  {
    const int c2 = 2 * ln;
    float2 acc[C];
#pragma unroll
    for (int r = 0; r < C; ++r) acc[r] = make_float2(0.f, 0.f);
#pragma unroll 1
    for (int blk = 0; blk < 4; ++blk) {
      const float* wp = W2 + (16 * wv + 4 * blk) * 128 + c2;
      const float2 w0 = *reinterpret_cast<const float2*>(wp);
      const float2 w1 = *reinterpret_cast<const float2*>(wp + 128);
      const float2 w2 = *reinterpret_cast<const float2*>(wp + 256);
      const float2 w3 = *reinterpret_cast<const float2*>(wp + 384);
#pragma unroll
      for (int r = 0; r < C; ++r) {
        const float4 hv = *reinterpret_cast<const float4*>(h + r * 256 + 16 * wv + 4 * blk);
        acc[r].x = fmaf(hv.x,w0.x, fmaf(hv.y,w1.x, fmaf(hv.z,w2.x, fmaf(hv.w,w3.x, acc[r].x))));
        acc[r].y = fmaf(hv.x,w0.y, fmaf(hv.y,w1.y, fmaf(hv.z,w2.y, fmaf(hv.w,w3.y, acc[r].y))));
      }
    }
#pragma unroll
    for (int r = 0; r < C; ++r)
      *reinterpret_cast<float2*>(red + (wv * C + r) * 128 + c2) = acc[r];
  }
  __syncthreads();
  // ---------- reduce2 + bias -> eout ----------
  if (t < 64 * C) {
    const int r  = t >> 6;
    const int c0 = 2 * (t & 63);
    float2 s = *reinterpret_cast<const float2*>(B2 + c0);
#pragma unroll
    for (int q = 0; q < 16; ++q) {
      const float2 p = *reinterpret_cast<const float2*>(red + (q * C + r) * 128 + c0);
      s.x += p.x; s.y += p.y;
    }
    *reinterpret_cast<float2*>(eout + r * 128 + c0) = s;
  }
  __syncthreads();
}

// ---- fused check+speculative-bit chunk for deep levels (l in {5,6,7}) ----
// Both bit-label variants share layer-1 partials (label enters only as a
// pre-folded bias), and check/bit share z. One chunk computes:
//   layer1: 2R partial rows (R check via Wc1, R bit via Wb1)
//   reduce1 -> h: 3R rows (check | bit+lab0 | bit+lab1)
//   layer2 (split-K=8 so red fits): 3R rows (Wc2 / Wb2)
//   reduce2: check rows -> eout (child e), bit rows -> spec[2][R][128]
// The later bit-run collapses to a 1-barrier select (l=5,6) or nothing (l=7:
// leaf-right reads spec directly). Bit-exact vs running bitnode with the
// real label. Halves the chunk count of the latency-dominated deep tail.
template <int R>
__device__ __forceinline__ void fused_chunk(
    const float* zl,
    const float* __restrict__ Wc1_, const float* __restrict__ Bc1_,
    const float* __restrict__ Wc2_, const float* __restrict__ Bc2_,
    const float* __restrict__ Wb1_, const float* __restrict__ Bb1_,
    const float* __restrict__ Wb2_, const float* __restrict__ Bb2_,
    const float* lab,
    float* red, float* h, float* eout, float* spec)
{
  const int t  = threadIdx.x;
  const int wv = t >> 6;
  const int ln = t & 63;
  // ---------- layer 1: 8 kg x 2 col-halves; 2R partial rows ----------
  {
    const int kg = wv >> 1;
    const int c1 = (wv & 1) * 128 + 2 * ln;
    const float* wcb = Wc1_ + 32 * kg * 256 + c1;
    const float* wbb = Wb1_ + 32 * kg * 256 + c1;
    const float* zb  = zl + 32 * kg;
    float2 ac[R], ab[R];
#pragma unroll
    for (int r = 0; r < R; ++r) { ac[r] = make_float2(0.f,0.f); ab[r] = make_float2(0.f,0.f); }
#pragma unroll 1
    for (int blk = 0; blk < 8; ++blk) {
      const float* wcp = wcb + 4 * blk * 256;
      const float* wbp = wbb + 4 * blk * 256;
      const float2 c0 = *reinterpret_cast<const float2*>(wcp);
      const float2 c1v = *reinterpret_cast<const float2*>(wcp + 256);
      const float2 c2v = *reinterpret_cast<const float2*>(wcp + 512);
      const float2 c3v = *reinterpret_cast<const float2*>(wcp + 768);
      const float2 b0 = *reinterpret_cast<const float2*>(wbp);
      const float2 b1 = *reinterpret_cast<const float2*>(wbp + 256);
      const float2 b2 = *reinterpret_cast<const float2*>(wbp + 512);
      const float2 b3 = *reinterpret_cast<const float2*>(wbp + 768);
      float4 z[R];
#pragma unroll
      for (int r = 0; r < R; ++r)
        z[r] = *reinterpret_cast<const float4*>(zb + r * 256 + 4 * blk);
#pragma unroll
      for (int r = 0; r < R; ++r) {
        ac[r].x = fmaf(z[r].x,c0.x, fmaf(z[r].y,c1v.x, fmaf(z[r].z,c2v.x, fmaf(z[r].w,c3v.x, ac[r].x))));
        ac[r].y = fmaf(z[r].x,c0.y, fmaf(z[r].y,c1v.y, fmaf(z[r].z,c2v.y, fmaf(z[r].w,c3v.y, ac[r].y))));
        ab[r].x = fmaf(z[r].x,b0.x, fmaf(z[r].y,b1.x, fmaf(z[r].z,b2.x, fmaf(z[r].w,b3.x, ab[r].x))));
        ab[r].y = fmaf(z[r].x,b0.y, fmaf(z[r].y,b1.y, fmaf(z[r].z,b2.y, fmaf(z[r].w,b3.y, ab[r].y))));
      }
    }
#pragma unroll
    for (int r = 0; r < R; ++r) {
      *reinterpret_cast<float2*>(red + (kg * 2 * R + r) * 256 + c1) = ac[r];
      *reinterpret_cast<float2*>(red + (kg * 2 * R + R + r) * 256 + c1) = ab[r];
    }
  }
  __syncthreads();
  // ---------- reduce1 -> h: 3R rows ----------
  for (int idx = t; idx < 3 * R * 128; idx += NTHR) {
    const int r  = idx >> 7;
    const int c0 = 2 * (idx & 127);
    const int pr = (r < 2 * R) ? r : r - R;     // bit partials shared by variants
    float2 s;
    if (r < R) {
      s = *reinterpret_cast<const float2*>(Bc1_ + c0);
    } else {
      s = *reinterpret_cast<const float2*>(Bb1_ + c0);
      const float2 lv = *reinterpret_cast<const float2*>(lab + ((r < 2 * R) ? 0 : 256) + c0);
      s.x += lv.x; s.y += lv.y;
    }
#pragma unroll
    for (int q = 0; q < 8; ++q) {
      const float2 p = *reinterpret_cast<const float2*>(red + (q * 2 * R + pr) * 256 + c0);
      s.x += p.x; s.y += p.y;
    }
    s.x = fmaxf(s.x, 0.f); s.y = fmaxf(s.y, 0.f);
    *reinterpret_cast<float2*>(h + r * 256 + c0) = s;
  }
  __syncthreads();
  // ---------- layer 2: 8 kg x 2 col-halves (1 col/lane); 3R rows ----------
  {
    const int kg = wv >> 1;
    const int c2 = (wv & 1) * 64 + ln;
    const float* wcb = Wc2_ + 32 * kg * 128 + c2;
    const float* wbb = Wb2_ + 32 * kg * 128 + c2;
    float acc[3 * R];
#pragma unroll
    for (int r = 0; r < 3 * R; ++r) acc[r] = 0.f;
#pragma unroll 1
    for (int blk = 0; blk < 8; ++blk) {
      const float* wcp = wcb + 4 * blk * 128;
      const float* wbp = wbb + 4 * blk * 128;
      const float c0v = wcp[0], c1v = wcp[128], c2v = wcp[256], c3v = wcp[384];
      const float b0v = wbp[0], b1v = wbp[128], b2v = wbp[256], b3v = wbp[384];
      const float* hb = h + 32 * kg + 4 * blk;
#pragma unroll
      for (int r = 0; r < 3 * R; ++r) {
        const float4 hv = *reinterpret_cast<const float4*>(hb + r * 256);
        if (r < R)
          acc[r] = fmaf(hv.x,c0v, fmaf(hv.y,c1v, fmaf(hv.z,c2v, fmaf(hv.w,c3v, acc[r]))));
        else
          acc[r] = fmaf(hv.x,b0v, fmaf(hv.y,b1v, fmaf(hv.z,b2v, fmaf(hv.w,b3v, acc[r]))));
      }
    }
#pragma unroll
    for (int r = 0; r < 3 * R; ++r)
      red[(kg * 3 * R + r) * 128 + c2] = acc[r];
  }
  __syncthreads();
  // ---------- reduce2: check -> eout, bit -> spec[2][R][128] ----------
  for (int idx = t; idx < 3 * R * 128; idx += NTHR) {
    const int r = idx >> 7;
    const int c = idx & 127;
    float s = (r < R) ? Bc2_[c] : Bb2_[c];
#pragma unroll
    for (int q = 0; q < 8; ++q) s += red[(q * 3 * R + r) * 128 + c];
    if (r < R)            eout[r * 128 + c] = s;
    else if (r < 2 * R)   spec[(r - R) * 128 + c] = s;
    else                  spec[R * 128 + (r - 2 * R) * 128 + c] = s;
  }
  __syncthreads();
}

__global__ void sc_setup(const int* __restrict__ info_set,
                         const float* __restrict__ E_obs,
                         const float* __restrict__ E_lab,
                         const float* __restrict__ Wb1,
                         int* __restrict__ pos2k, float* __restrict__ lab1,
                         float* __restrict__ eroot)
{
  const int t = threadIdx.x;   // 256 threads
  pos2k[t] = -1;
  __syncthreads();
  if (t < 128) pos2k[info_set[t]] = t;
  eroot[t] = E_obs[2 * 128 + (t & 127)];
  for (int j = 0; j < 2; ++j) {
    float s = 0.0f;
    for (int k = 0; k < 128; ++k)
      s = fmaf(E_lab[j * 128 + k], Wb1[(256 + k) * 256 + t], s);
    lab1[j * 256 + t] = s;
  }
}

__global__ __launch_bounds__(NTHR)
__attribute__((amdgpu_waves_per_eu(4, 4)))
void sc_main(const int* __restrict__ info_bits, const float* __restrict__ rin,
             const float* __restrict__ Wc1, const float* __restrict__ bc1,
             const float* __restrict__ Wc2, const float* __restrict__ bc2,
             const float* __restrict__ Wb1, const float* __restrict__ bb1,
             const float* __restrict__ Wb2, const float* __restrict__ bb2,
             const float* __restrict__ Wl, const float* __restrict__ bl,
             const int* __restrict__ pos2k, const float* __restrict__ lab1_g,
             const float* __restrict__ eroot_g,
             float* __restrict__ wsall, float* __restrict__ out)
{
  const int b = blockIdx.x;
  const int t = threadIdx.x;
  float* e1g = wsall + (size_t)b * EG_STRIDE;      // level-1 e (global)

  __shared__ __align__(16) float red[16384];       // 64 KB split-K partials
  __shared__ __align__(16) float h_lds[3072];      // 12 KB hidden (3R<=12 rows)
  __shared__ __align__(16) float scratch[2048];    //  8 KB: lvl-1 z-stage  UNION
                                                   //  spec5[0..1024) spec6[1024..1536) spec7[1536..1792)
                                                   //  (disjoint lifetimes: stage only l<=1, specs only l>=5)
  __shared__ __align__(16) float e2[8192];         // 32 KB level-2 e
  __shared__ __align__(16) float e3[4096];         // 16 KB level-3 e
  __shared__ __align__(16) float e4[2048];         //  8 KB level-4 e
  __shared__ __align__(16) float e5678[1920];      // levels 5..8: 8,4,2,1 rows
  __shared__ __align__(16) float lab_lds[512];
  __shared__ __align__(16) float eroot[256];
  __shared__ float rrow[256];
  __shared__ float wl_lds[132];                    // Wl[128] + bl at [128]
  __shared__ int   xh[520];
  __shared__ int   ibits[128];
  __shared__ int   p2k_l[256];

  float* xO = out;
  float* fO = out + 32768;
  float* uO = out + 65536;
  float* pO = out + 98304;
  float* rO = out + 131072;

  // ---- prologue: preload constants, hoist input-independent outputs ----
  if (t < 512) lab_lds[t] = lab1_g[t];
  if (t < 256) {
    eroot[t]  = eroot_g[t];
    const int k = pos2k[t];
    p2k_l[t]  = k;
    const float rv = rin[b * 256 + t];
    rrow[t]   = rv;
    rO[b * 256 + t] = rv;
    fO[b * 256 + t] = (k >= 0) ? 2.0f : 1.0f;
  }
  if (t < 128) { ibits[t] = info_bits[b * 128 + t]; wl_lds[t] = Wl[t]; }
  if (t == 128) wl_lds[128] = bl[0];
  if (t == 0) { xh[512] = 0; xh[513] = 1; }        // constant u1h for lvl-0 bit
  __syncthreads();

  // ---- generic level runner (levels 1..4, all-LDS z) ----
  auto run_level = [&](int l, bool isbit) {
    const int rows = 128 >> l;
    const float* W1 = isbit ? Wb1 : Wc1;
    const float* B1 = isbit ? bb1 : bc1;
    const float* W2 = isbit ? Wb2 : Wc2;
    const float* B2 = isbit ? bb2 : bc2;
    const int* u1h = xh + xoff(l);
    float* ein; float* eo;
    switch (l) {
      case 1:  ein = nullptr; eo = e2;    break;
      case 2:  ein = e2;      eo = e3;    break;
      case 3:  ein = e3;      eo = e4;    break;
      default: ein = e4;      eo = e5678; break;   // l == 4
    }
    int done = 0;
    while (done < rows) {
      int c = rows - done; if (c > 8) c = 8;
      const float* zl;
      if (l == 1) {   // stage global e1 chunk -> LDS (coalesced, one barrier)
        const float2* src = reinterpret_cast<const float2*>(e1g + done * 256);
        const int n2 = c * 128;
        for (int i2 = t; i2 < n2; i2 += NTHR)
          reinterpret_cast<float2*>(scratch)[i2] = src[i2];
        __syncthreads();
        zl = scratch;
      } else {
        zl = ein + done * 256;
      }
      float* eoc = eo + done * 128;
      if (c == 8) mlp_chunk<8>(zl, 256, W1, B1, W2, B2, lab_lds, isbit, u1h, done, red, h_lds, eoc);
      else        mlp_chunk<4>(zl, 256, W1, B1, W2, B2, lab_lds, isbit, u1h, done, red, h_lds, eoc);
      done += c;
    }
  };

  // ---- level 0 special: check rows all identical (z = eroot); bit rows take
  // only 2 values (label j in {0,1}). Compute 1 (check) or 2 (bit) rows, then
  // broadcast/scatter into e1. ----
  auto run_level0 = [&](bool isbit) {
    if (!isbit) {
      mlp_chunk<1>(eroot, 0, Wc1, bc1, Wc2, bc2, lab_lds, false, xh, 0, red, h_lds, scratch);
      for (int i4 = t; i4 < 4096; i4 += NTHR)
        reinterpret_cast<float4*>(e1g)[i4] =
            reinterpret_cast<const float4*>(scratch)[i4 & 31];
    } else {
      mlp_chunk<2>(eroot, 0, Wb1, bb1, Wb2, bb2, lab_lds, true, xh + 512, 0, red, h_lds, scratch);
      for (int i4 = t; i4 < 4096; i4 += NTHR)
        reinterpret_cast<float4*>(e1g)[i4] =
            reinterpret_cast<const float4*>(scratch)[(xh[i4 >> 5] & 1) * 32 + (i4 & 31)];
    }
    __syncthreads();
  };

  // ---- fused check+spec for l in {5,6,7} ----
  auto run_fused = [&](int l) {
    if (l == 5)
      fused_chunk<4>(e5678, Wc1, bc1, Wc2, bc2, Wb1, bb1, Wb2, bb2, lab_lds,
                     red, h_lds, e5678 + 1024, scratch);
    else if (l == 6)
      fused_chunk<2>(e5678 + 1024, Wc1, bc1, Wc2, bc2, Wb1, bb1, Wb2, bb2, lab_lds,
                     red, h_lds, e5678 + 1536, scratch + 1024);
    else
      fused_chunk<1>(e5678 + 1536, Wc1, bc1, Wc2, bc2, Wb1, bb1, Wb2, bb2, lab_lds,
                     red, h_lds, e5678 + 1792, scratch + 1536);
  };

  // ---- bit-time select for l in {5,6}: child e row r = spec[u1h[r]][r] ----
  auto do_select = [&](int l) {
    const int R = 128 >> l;
    const float* spec = scratch + ((l == 5) ? 0 : 1024);
    float* eo = (l == 5) ? (e5678 + 1024) : (e5678 + 1536);
    const int* u1h = xh + xoff(l);
    if (t < R * 128) {
      const int r = t >> 7;
      eo[t] = spec[(u1h[r] & 1) * R * 128 + t];
    }
    __syncthreads();
  };

  auto do_leaf = [&](int i) {
    // left leaf reads e8 (check output); right leaf reads spec7[u1h] directly
    const float* e = (i & 1) ? (scratch + 1536 + (xh[xoff(7)] & 1) * 128)
                             : (e5678 + 1792);
    if (t < 64) {
      float partial = e[t] * wl_lds[t] + e[t + 64] * wl_lds[t + 64];
#pragma unroll
      for (int m = 32; m >= 1; m >>= 1) partial += __shfl_xor(partial, m);
      if (t == 0) {
        const float tv = partial + wl_lds[128];
        const float p  = 1.0f / (1.0f + expf(-tv));
        const float rv = rrow[i];
        const int  hd     = (rv > p) ? 1 : 0;
        const bool frozen = fabsf(p - 0.5f) > 0.25f;
        const int  k  = p2k_l[i];
        const int  fc = (k >= 0) ? ibits[k] : 2;
        const int  x  = (fc == 2 || frozen) ? hd : fc;
        xh[xoff(7) + (i & 1)] = x;
        pO[b * 256 + i] = p;
        uO[b * 256 + i] = (float)x;
      }
    }
    __syncthreads();
  };

  auto do_combine = [&](int l, int side) {
    const int n = 256 >> l, half = n >> 1;
    if (t < half) {
      const int u1 = xh[xoff(l) + t];
      const int u2 = xh[xoff(l) + half + t];
      if (l > 0) {
        const int base = xoff(l - 1) + side * n;
        xh[base + 2 * t]     = u1 ^ u2;
        xh[base + 2 * t + 1] = u2;
      } else {
        xO[b * 256 + 2 * t]     = (float)(u1 ^ u2);
        xO[b * 256 + 2 * t + 1] = (float)u2;
      }
    }
    __syncthreads();
  };

  // ---- SC traversal ----
  int i = 0, l = 0;
  bool isbit = false;
  while (true) {
    if (l >= 5) {
      if (isbit) { if (l < 7) do_select(l); }   // l==7 bit: leaf reads spec
      else       run_fused(l);
    } else if (l == 0) {
      run_level0(isbit);
    } else {
      run_level(l, isbit);
    }
    if (l < 7) { ++l; isbit = false; continue; }
    do_leaf(i);
    if (i == 255) break;
    ++i;
    const int s = __builtin_ctz(i);
    for (int j = 1; j <= s; ++j) do_combine(8 - j, (j < s) ? 1 : 0);
    l = 7 - s;
    isbit = true;
  }
  for (int j = 1; j <= 8; ++j) do_combine(8 - j, 1);
}

extern "C" void kernel_launch(void* const* d_in, const int* in_sizes, int n_in,
                              void* d_out, int out_size, void* d_ws, size_t ws_size,
                              hipStream_t stream)
{
  const int*   info_bits = (const int*)  d_in[0];
  const float* rin       = (const float*)d_in[1];
  const int*   info_set  = (const int*)  d_in[2];
  const float* E_obs     = (const float*)d_in[3];
  const float* E_lab     = (const float*)d_in[4];
  const float* Wc1 = (const float*)d_in[5];
  const float* bc1 = (const float*)d_in[6];
  const float* Wc2 = (const float*)d_in[7];
  const float* bc2 = (const float*)d_in[8];
  const float* Wb1 = (const float*)d_in[9];
  const float* bb1 = (const float*)d_in[10];
  const float* Wb2 = (const float*)d_in[11];
  const float* bb2 = (const float*)d_in[12];
  const float* Wl  = (const float*)d_in[13];
  const float* bl  = (const float*)d_in[14];

  int*   pos2k = (int*)d_ws;                 // 256 ints
  float* lab1  = (float*)d_ws + 256;         // 512 floats
  float* eroot = (float*)d_ws + 768;         // 256 floats
  float* wsall = (float*)d_ws + 1024;        // 128 x EG_STRIDE floats

  hipLaunchKernelGGL(sc_setup, dim3(1), dim3(256), 0, stream,
                     info_set, E_obs, E_lab, Wb1, pos2k, lab1, eroot);
  hipLaunchKernelGGL(sc_main, dim3(128), dim3(NTHR), 0, stream,
                     info_bits, rin,
                     Wc1, bc1, Wc2, bc2, Wb1, bb1, Wb2, bb2, Wl, bl,
                     pos2k, lab1, eroot, wsall, (float*)d_out);
}